// Round 5
// baseline (3094.425 us; speedup 1.0000x reference)
//
#include <hip/hip_runtime.h>
#include <math.h>

#define BB 128
#define TT 1024
#define DD 128
#define HH 64
#define G3 192   // 3*H
#define KK 32
#define CH 32    // staging chunk (steps)

// ---------------------------------------------------------------------------
// Single FUSED kernel: xproj + GRU + potentials + Viterbi, 8 waves.
// R4 post-mortem: demand-side spill fix worked (full unroll, const indices)
// but allocator BUDGET stayed 128 (= 512-reg pool / 4 waves-per-EU default
// target) and spilled the xproj branch's ~176-reg demand (VGPR_Count==128,
// WRITE_SIZE +7.1MB == ~72 spilled floats). This kernel is LDS-bound to
// 1 block/CU = 2 waves/EU, so regs above 128 are FREE. Fix: pin the
// occupancy target with amdgpu_waves_per_eu(2,2) -> budget 256.
//   waves 0-2: GRU gates (weights pinned in VGPRs; xv/mask from LDS)
//   wave 3:    pot matvec -> LDS ring + mask staging + pot flush
//   waves 4-6: xproj producer (Wk column pinned in VGPRs; X from LDS)
//   wave 7:    viterbi transition (pure LDS)
// Xstage aliases the backtrack `table` (disjoint lifetimes) -> LDS ~126.4 KB.
// Two pre-loop barriers (B1: Xstage ready, B2: xpstage chunk 0 ready), then
// 1 barrier/step; all waves run 2 + (TT+2) barriers before the backtrack.
// ---------------------------------------------------------------------------
#define BCAST(v, l) __int_as_float(__builtin_amdgcn_readlane(__float_as_int(v), (l)))

__global__ __launch_bounds__(512) __attribute__((amdgpu_waves_per_eu(2, 2)))
void fused_kernel(const float* __restrict__ X,
                  const float* __restrict__ Wk,
                  const float* __restrict__ Wr,
                  const float* __restrict__ gbias,
                  const int* __restrict__ mask,
                  const float* __restrict__ Dk,
                  const float* __restrict__ db,
                  const float* __restrict__ chain,
                  const float* __restrict__ lb,
                  const float* __restrict__ rb,
                  float* __restrict__ out_pot,
                  float* __restrict__ out_dec,
                  float* __restrict__ out_slen,
                  float* __restrict__ out_chn) {
    const int b = blockIdx.x;
    const int tid = threadIdx.x;
    const int w = tid >> 6;                    // 0..7
    const int l = tid & 63;
    const int bTT = b * TT;

    __shared__ unsigned char bp[(TT - 1) * KK];                      // 32736 B
    __shared__ __align__(16) unsigned char table[32 * 32 * KK];      // 32768 B (aliased as Xstage in main loop)
    __shared__ int ent[32];
    __shared__ int last_tag_s;
    __shared__ float gbuf[2][4 * HH];                    // 2048 B
    __shared__ __align__(16) float hbuf[4][HH];          // 1024 B
    __shared__ __align__(16) float potring[64][KK];      // 8192 B
    __shared__ __align__(16) float xpstage[2][CH * G3];  // 49152 B
    __shared__ int maskst[2][CH];                        // 256 B

    // Alias: Xstage[2][CH*DD] lives in `table` during the main loop.
    float* Xstage0 = (float*)&table[0];                  // [CH*DD]
    float* Xstage1 = (float*)&table[CH * DD * 4];        // [CH*DD]

    if (w < 3) {
        // ================= GRU producer waves =================
        const int j = l;
        float wg[HH];
#pragma unroll
        for (int i2 = 0; i2 < HH; ++i2) wg[i2] = Wr[i2 * G3 + w * HH + j];
#pragma unroll
        for (int i2 = 0; i2 < HH; ++i2) asm volatile("" : "+v"(wg[i2]));
        const float bw = gbias[G3 + w * HH + j];
        __builtin_amdgcn_s_setprio(1);
        float h = 0.f;
        __syncthreads();                                  // B1: Xstage ready
        __syncthreads();                                  // B2: xpstage[0] ready
        float xv0 = xpstage[0][tid];                      // xv(0)
        int m0 = maskst[0][0];                            // m(0), broadcast
        for (int i = 0; i < TT + 2; ++i) {
            if (i < TT) {
                float a0 = bw, a1 = 0.f, a2 = 0.f, a3 = 0.f;
#pragma unroll
                for (int c = 0; c < HH; c += 4) {
                    a0 += BCAST(h, c + 0) * wg[c + 0];
                    a1 += BCAST(h, c + 1) * wg[c + 1];
                    a2 += BCAST(h, c + 2) * wg[c + 2];
                    a3 += BCAST(h, c + 3) * wg[c + 3];
                }
                float a = (a0 + a1) + (a2 + a3);
                float g = (w == 2) ? a : 1.f / (1.f + __expf(-(xv0 + a)));
                gbuf[i & 1][w * HH + j] = g;
                if (w == 2) gbuf[i & 1][3 * HH + j] = xv0;
            }
            __syncthreads();
            if (i < TT) {
                float z  = gbuf[i & 1][j];
                float r  = gbuf[i & 1][HH + j];
                float rh = gbuf[i & 1][2 * HH + j];
                float xh = gbuf[i & 1][3 * HH + j];
                float y = xh + r * rh;
                float hh = 1.f - 2.f / (1.f + __expf(2.f * y));   // tanh
                float hn = z * h + (1.f - z) * hh;
                hn = (m0 != 0) ? hn : h;
                h = hn;
                if (w == 0) hbuf[i & 3][j] = hn;
                if (i < TT - 1) {                        // prefetch step i+1
                    const int t1 = i + 1;
                    xv0 = xpstage[(t1 >> 5) & 1][(t1 & 31) * G3 + tid];
                    m0  = maskst[(t1 >> 5) & 1][t1 & 31];
                }
            }
        }
    } else if (w == 3) {
        // ============ pot matvec + mask staging + pot flush wave ============
        const int k = l & 31;
        int sl = 0;
#pragma unroll
        for (int q = 0; q < 16; ++q) sl += mask[bTT + q * 64 + l];
#pragma unroll
        for (int d = 32; d >= 1; d >>= 1) sl += __shfl_xor(sl, d, 64);
        if (l == 0) out_slen[b] = (float)sl;
        float dk[HH];
#pragma unroll
        for (int i2 = 0; i2 < HH; ++i2) dk[i2] = Dk[i2 * KK + k];
#pragma unroll
        for (int i2 = 0; i2 < HH; ++i2) asm volatile("" : "+v"(dk[i2]));
        const float dbk = db[k], lbk = lb[k], rbk = rb[k];
        float* potg = out_pot + (size_t)bTT * KK;
        if (l < CH) maskst[0][l] = mask[bTT + l];
        __syncthreads();                                  // B1
        __syncthreads();                                  // B2
        for (int i = 0; i < TT + 2; ++i) {
            if ((i & 31) == 0) {
                const int cn = (i >> 5) + 1;              // stage mask chunk cn
                if (cn < 32 && l < CH) maskst[cn & 1][l] = mask[bTT + cn * CH + l];
                const int cf = (i >> 5) - 2;              // flush pot chunk cf
                if (cf >= 0) {
                    const float* srcl = &potring[(cf & 1) * 32][0];
                    float* dstg = potg + (size_t)cf * CH * KK;
#pragma unroll
                    for (int q = 0; q < 4; ++q) {
                        float4 v = *(const float4*)&srcl[q * 256 + l * 4];
                        *(float4*)&dstg[q * 256 + l * 4] = v;
                    }
                }
            }
            const int t = i - 2;
            if (t >= 0 && t < TT) {
                const float4* hv4 = (const float4*)&hbuf[t & 3][0];
                float p0 = dbk, p1 = 0.f, p2 = 0.f, p3 = 0.f;
#pragma unroll
                for (int c = 0; c < 16; ++c) {
                    float4 hv = hv4[c];
                    p0 += hv.x * dk[4 * c + 0];
                    p1 += hv.y * dk[4 * c + 1];
                    p2 += hv.z * dk[4 * c + 2];
                    p3 += hv.w * dk[4 * c + 3];
                }
                float pot = (p0 + p1) + (p2 + p3);
                if (t == 0) pot += lbk;
                if (t == sl - 1) pot += rbk;
                if (l < 32) potring[t & 63][k] = pot;
            }
            __syncthreads();
        }
        // flush last pot chunk (31)
        {
            const float* srcl = &potring[(31 & 1) * 32][0];
            float* dstg = potg + (size_t)31 * CH * KK;
#pragma unroll
            for (int q = 0; q < 4; ++q) {
                float4 v = *(const float4*)&srcl[q * 256 + l * 4];
                *(float4*)&dstg[q * 256 + l * 4] = v;
            }
        }
    } else if (w < 7) {
        // ================= xproj producer waves =================
        const int xw = w - 4;                              // 0..2
        const int col = xw * 64 + l;                       // 0..191
        // Wk column split into two 64-float register arrays; ALL index loops
        // fully unrolled (rule #20). Needs the 256-reg budget from
        // amdgpu_waves_per_eu(2,2) to stay spill-free.
        float wkl[64], wkh[64];
#pragma unroll
        for (int k2 = 0; k2 < 64; ++k2) wkl[k2] = Wk[(size_t)k2 * G3 + col];
#pragma unroll
        for (int k2 = 0; k2 < 64; ++k2) wkh[k2] = Wk[(size_t)(64 + k2) * G3 + col];
#pragma unroll
        for (int k2 = 0; k2 < 64; ++k2) asm volatile("" : "+v"(wkl[k2]));
#pragma unroll
        for (int k2 = 0; k2 < 64; ++k2) asm volatile("" : "+v"(wkh[k2]));
        const float b0 = gbias[col];                       // input bias
        const float* Xg = X + (size_t)bTT * DD;
        // stage X chunks 0 and 1 (3 waves cooperate: 192 lanes, 1024 float4/chunk)
        {
            const float* src0 = Xg;
            const float* src1 = Xg + (size_t)CH * DD;
#pragma unroll
            for (int q = 0; q < 6; ++q) {
                int idx = q * 192 + col;
                if (idx < 1024) {
                    float4 v0 = *(const float4*)&src0[idx * 4];
                    *(float4*)&Xstage0[idx * 4] = v0;
                    float4 v1 = *(const float4*)&src1[idx * 4];
                    *(float4*)&Xstage1[idx * 4] = v1;
                }
            }
        }
        __syncthreads();                                   // B1: Xstage ready
        // compute chunk 0 -> xpstage[0] (accumulation order == old xproj kernel)
#pragma unroll 1
        for (int r = 0; r < CH; ++r) {
            const float4* xr = (const float4*)&Xstage0[r * DD];
            float acc = 0.f;
#pragma unroll
            for (int c4 = 0; c4 < 16; ++c4) {
                float4 xv = xr[c4];
                acc += xv.x * wkl[4 * c4 + 0];
                acc += xv.y * wkl[4 * c4 + 1];
                acc += xv.z * wkl[4 * c4 + 2];
                acc += xv.w * wkl[4 * c4 + 3];
            }
#pragma unroll
            for (int c4 = 0; c4 < 16; ++c4) {
                float4 xv = xr[16 + c4];
                acc += xv.x * wkh[4 * c4 + 0];
                acc += xv.y * wkh[4 * c4 + 1];
                acc += xv.z * wkh[4 * c4 + 2];
                acc += xv.w * wkh[4 * c4 + 3];
            }
            xpstage[0][r * G3 + col] = acc + b0;
        }
        __syncthreads();                                   // B2: xpstage[0] ready
        for (int i = 0; i < TT + 2; ++i) {
            const int wi = i >> 5;
            if ((i & 31) == 0) {
                const int cs = wi + 2;                     // stage X chunk cs
                if (cs < 32) {
                    const float* src = Xg + (size_t)cs * CH * DD;
                    float* dst = (cs & 1) ? Xstage1 : Xstage0;
#pragma unroll
                    for (int q = 0; q < 6; ++q) {
                        int idx = q * 192 + col;
                        if (idx < 1024) {
                            float4 v = *(const float4*)&src[idx * 4];
                            *(float4*)&dst[idx * 4] = v;
                        }
                    }
                }
            }
            const int c = wi + 1;                          // compute chunk c, row r
            if (c < 32) {
                const int r = i & 31;
                const float* xsrc = (c & 1) ? Xstage1 : Xstage0;
                const float4* xr = (const float4*)&xsrc[r * DD];
                float acc = 0.f;
#pragma unroll
                for (int c4 = 0; c4 < 16; ++c4) {
                    float4 xv = xr[c4];
                    acc += xv.x * wkl[4 * c4 + 0];
                    acc += xv.y * wkl[4 * c4 + 1];
                    acc += xv.z * wkl[4 * c4 + 2];
                    acc += xv.w * wkl[4 * c4 + 3];
                }
#pragma unroll
                for (int c4 = 0; c4 < 16; ++c4) {
                    float4 xv = xr[16 + c4];
                    acc += xv.x * wkh[4 * c4 + 0];
                    acc += xv.y * wkh[4 * c4 + 1];
                    acc += xv.z * wkh[4 * c4 + 2];
                    acc += xv.w * wkh[4 * c4 + 3];
                }
                xpstage[c & 1][r * G3 + col] = acc + b0;
            }
            __syncthreads();
        }
    } else {
        // ================= viterbi wave =================
        const int k = l & 31;
        const int hf = l >> 5;
        float ccol[16];
        int addr[16];
#pragma unroll
        for (int m = 0; m < 16; ++m) {
            ccol[m] = chain[(hf * 16 + m) * KK + k];
            addr[m] = (hf * 16 + m) * 4;
        }
#pragma unroll
        for (int m = 0; m < 16; ++m) asm volatile("" : "+v"(ccol[m]));
        const int addrx = (l ^ 32) * 4;
        float s = 0.f;
        __syncthreads();                                  // B1
        __syncthreads();                                  // B2
        for (int i = 0; i < TT + 2; ++i) {
            __syncthreads();
            const int t = i - 2;
            if (t >= 0 && t < TT) {
                float pot = potring[t & 63][k];
                if (t == 0) {
                    s = pot;
                } else {
                    const int si = __float_as_int(s);
                    float c[16];
#pragma unroll
                    for (int m = 0; m < 16; ++m)
                        c[m] = __int_as_float(__builtin_amdgcn_ds_bpermute(addr[m], si)) + ccol[m];
                    float v1[8]; int i1[8];
#pragma unroll
                    for (int p = 0; p < 8; ++p) {
                        bool tk = c[2 * p + 1] > c[2 * p];
                        v1[p] = tk ? c[2 * p + 1] : c[2 * p];
                        i1[p] = hf * 16 + (tk ? 2 * p + 1 : 2 * p);
                    }
                    float v2[4]; int i2[4];
#pragma unroll
                    for (int p = 0; p < 4; ++p) {
                        bool tk = v1[2 * p + 1] > v1[2 * p];
                        v2[p] = tk ? v1[2 * p + 1] : v1[2 * p];
                        i2[p] = tk ? i1[2 * p + 1] : i1[2 * p];
                    }
                    float v3[2]; int i3[2];
#pragma unroll
                    for (int p = 0; p < 2; ++p) {
                        bool tk = v2[2 * p + 1] > v2[2 * p];
                        v3[p] = tk ? v2[2 * p + 1] : v2[2 * p];
                        i3[p] = tk ? i2[2 * p + 1] : i2[2 * p];
                    }
                    bool tk = v3[1] > v3[0];
                    float bv = tk ? v3[1] : v3[0];
                    int bi = tk ? i3[1] : i3[0];
                    float ov = __int_as_float(__builtin_amdgcn_ds_bpermute(addrx, __float_as_int(bv)));
                    int   oi = __builtin_amdgcn_ds_bpermute(addrx, bi);
                    bool take = (ov > bv) || (ov == bv && oi < bi);
                    if (take) { bv = ov; bi = oi; }
                    if (l < 32) bp[(t - 1) * KK + k] = (unsigned char)bi;
                    s = bv + pot;
                }
            }
        }
        float bv = s; int bi = k;
#pragma unroll
        for (int d = 16; d >= 1; d >>= 1) {
            float ov = __shfl_xor(bv, d, 64);
            int   oi = __shfl_xor(bi, d, 64);
            bool take = (ov > bv) || (ov == bv && oi < bi);
            if (take) { bv = ov; bi = oi; }
        }
        if (l == 0) last_tag_s = bi;
    }
    __syncthreads();   // end main loop; Xstage lifetime over, `table` lifetime begins
    // ---- Phase A: chunk-parallel backtrack (16 groups over 32 chunks) ----
    {
        const int k = tid & 31;
        const int grp = tid >> 5;                         // 0..15
        for (int c = grp; c < 32; c += 16) {
            int tag = k;
            for (int ll = 31; ll >= 0; --ll) {
                const int t = c * 32 + ll;
                if (t < TT - 1) tag = bp[t * KK + tag];
                table[(c * 32 + ll) * KK + k] = (unsigned char)tag;
            }
        }
    }
    __syncthreads();
    if (tid == 0) {                                       // Phase B: stitch
        int e = last_tag_s;
        ent[31] = e;
        for (int c = 30; c >= 0; --c) { e = table[(c + 1) * 32 * KK + e]; ent[c] = e; }
    }
    __syncthreads();
    for (int t = tid; t < TT; t += 512) {                 // Phase C: emit
        const int c = t >> 5, ll = t & 31;
        out_dec[(size_t)bTT + t] = (float)table[(c * 32 + ll) * KK + ent[c]];
    }
    if (b == 0) {
        for (int i2 = tid; i2 < KK * KK; i2 += 512) out_chn[i2] = chain[i2];
    }
}

// ---------------------------------------------------------------------------
extern "C" void kernel_launch(void* const* d_in, const int* in_sizes, int n_in,
                              void* d_out, int out_size, void* d_ws, size_t ws_size,
                              hipStream_t stream) {
    const float* X     = (const float*)d_in[0];
    const int*   mask  = (const int*)d_in[1];
    const float* Wk    = (const float*)d_in[2];   // [128,192]
    const float* Wr    = (const float*)d_in[3];   // [64,192]
    const float* gb    = (const float*)d_in[4];   // [2,192]
    const float* Dk    = (const float*)d_in[5];   // [64,32]
    const float* db    = (const float*)d_in[6];   // [32]
    const float* chain = (const float*)d_in[7];   // [32,32]
    const float* lb    = (const float*)d_in[8];
    const float* rb    = (const float*)d_in[9];

    float* out = (float*)d_out;
    float* out_dec  = out;                                   // [B,T]
    float* out_pot  = out + (size_t)BB * TT;                 // [B,T,K]
    float* out_slen = out + (size_t)BB * TT + (size_t)BB * TT * KK;        // [B]
    float* out_chn  = out_slen + BB;                         // [K,K]

    fused_kernel<<<dim3(BB), dim3(512), 0, stream>>>(X, Wk, Wr, gb, mask, Dk, db,
                                                     chain, lb, rb, out_pot, out_dec,
                                                     out_slen, out_chn);
}

// Round 6
// 926.036 us; speedup vs baseline: 3.3416x; 3.3416x over previous
//
#include <hip/hip_runtime.h>
#include <math.h>

#define BB 128
#define TT 1024
#define DD 128
#define HH 64
#define G3 192   // 3*H
#define KK 32
#define CH 32    // staging chunk (steps)

// ---------------------------------------------------------------------------
// ONE launch, TWO block roles (producer/consumer), 256 blocks x 320 threads.
//   blocks 0..127   PRODUCER p: xp[p] = X[p] @ Wk + b0, the OLD proven xproj
//     tiling (64x64 tiles, 4x4 acc, k-ascending accumulation -> bitwise
//     identical to the 166us standalone kernel), with Wk staged ONCE in its
//     own LDS (104 KB). Publishes per-chunk flags: stores -> __threadfence()
//     -> device-scope atomicExch (L2 writeback to coherent point).
//   blocks 128..255 CONSUMER b=blk-128: the UNMODIFIED R0 732us fused
//     GRU+pot+viterbi kernel (5 waves), plus a 1-lane spin on flag[b][cn]
//     before staging each xp chunk (+__threadfence acquire).
// Why: R0 showed the fused loop is latency-bound at 7% occupancy with 128
// CUs idle; 3 rounds proved in-register Wk fusion is un-compilable (demand
// 128+40 regs vs hard 128 budget). Producers ride the idle CUs instead.
// Deadlock-impossible: 128 consumers < 256 CUs, producers never wait.
// Flags: zero-init __device__ array; each consumer re-zeros its 32 flags in
// its epilogue so bench iterations / rocprof replays stay correct.
// Producer rate ~8us/chunk vs consumer ~23us/chunk -> ahead after ~15us.
// ---------------------------------------------------------------------------
#define BCAST(v, l) __int_as_float(__builtin_amdgcn_readlane(__float_as_int(v), (l)))

__device__ int g_flags[BB * 32];   // zero-initialized at module load

__global__ __launch_bounds__(320, 1)
void mega_kernel(const float* __restrict__ X,
                 const float* __restrict__ Wk,
                 const float* __restrict__ Wr,
                 const float* __restrict__ gbias,
                 const int* __restrict__ mask,
                 const float* __restrict__ Dk,
                 const float* __restrict__ db,
                 const float* __restrict__ chain,
                 const float* __restrict__ lb,
                 const float* __restrict__ rb,
                 float* __restrict__ xp,
                 float* __restrict__ out_pot,
                 float* __restrict__ out_dec,
                 float* __restrict__ out_slen,
                 float* __restrict__ out_chn) {
    __shared__ __align__(16) unsigned char smem[138240];
    const int tid = threadIdx.x;

    if (blockIdx.x < BB) {
        // =================== PRODUCER ===================
        const int p = blockIdx.x;
        const int bTT = p * TT;
        float* Xs = (float*)smem;                  // [64][132]  33792 B
        float* Ws = (float*)(smem + 33792);        // [3][128][68] 104448 B
        // stage ALL of Wk once (98 KB real data)
        for (int idx = tid; idx < 6144; idx += 320) {
            const int cg = idx >> 11, rem = idx & 2047;
            const int k = rem >> 4, c4 = (rem & 15) << 2;
            float4 v = *(const float4*)&Wk[(size_t)k * G3 + cg * 64 + c4];
            *(float4*)&Ws[cg * (128 * 68) + k * 68 + c4] = v;
        }
        const int tr = tid >> 4, tc = tid & 15;    // valid for tid<256
        const int r0 = tr * 4, c0 = tc * 4;
        for (int rt = 0; rt < 16; ++rt) {          // 64-row tile = chunks 2rt,2rt+1
            const int row0 = rt * 64;
            for (int idx = tid; idx < 2048; idx += 320) {
                const int r = idx >> 5, c4 = (idx & 31) << 2;
                float4 v = *(const float4*)&X[((size_t)(bTT + row0 + r)) * DD + c4];
                *(float4*)&Xs[r * 132 + c4] = v;
            }
            __syncthreads();                       // Xs (and, 1st iter, Ws) ready
            if (tid < 256) {
                for (int cg = 0; cg < 3; ++cg) {
                    const float* Wc = &Ws[cg * (128 * 68)];
                    float acc[4][4];
#pragma unroll
                    for (int r = 0; r < 4; ++r)
#pragma unroll
                        for (int c = 0; c < 4; ++c) acc[r][c] = 0.f;
#pragma unroll 4
                    for (int k = 0; k < DD; k += 4) {
                        float a[4][4];
#pragma unroll
                        for (int r = 0; r < 4; ++r) {
                            float4 t = *(const float4*)&Xs[(r0 + r) * 132 + k];
                            a[r][0] = t.x; a[r][1] = t.y; a[r][2] = t.z; a[r][3] = t.w;
                        }
#pragma unroll
                        for (int kk = 0; kk < 4; ++kk) {
                            float4 bv = *(const float4*)&Wc[(k + kk) * 68 + c0];
#pragma unroll
                            for (int r = 0; r < 4; ++r) {
                                acc[r][0] += a[r][kk] * bv.x;
                                acc[r][1] += a[r][kk] * bv.y;
                                acc[r][2] += a[r][kk] * bv.z;
                                acc[r][3] += a[r][kk] * bv.w;
                            }
                        }
                    }
                    float4 bias = *(const float4*)&gbias[cg * 64 + c0];
#pragma unroll
                    for (int r = 0; r < 4; ++r) {
                        float4 o;
                        o.x = acc[r][0] + bias.x; o.y = acc[r][1] + bias.y;
                        o.z = acc[r][2] + bias.z; o.w = acc[r][3] + bias.w;
                        *(float4*)&xp[((size_t)(bTT + row0 + r0 + r)) * G3 + cg * 64 + c0] = o;
                    }
                }
            }
            __threadfence();                       // make xp writes device-visible
            __syncthreads();                       // all lanes' fences done
            if (tid == 0) {
                atomicExch(&g_flags[p * 32 + 2 * rt], 1);
                atomicExch(&g_flags[p * 32 + 2 * rt + 1], 1);
            }
        }
        return;
    }

    // =================== CONSUMER (R0's proven 732us kernel + spin) ===========
    const int b = blockIdx.x - BB;
    const int w = tid >> 6;                    // 0..4
    const int l = tid & 63;
    const int bTT = b * TT;

    unsigned char* bp    = smem;                                  // 32736 B
    unsigned char* table = smem + 32736;                          // 32768 B
    int*   ent        = (int*)(smem + 65504);                     // 128 B
    int*   last_tag_s = (int*)(smem + 65632);                     // 4 B (pad->65648)
    float (*gbuf)[4 * HH]   = (float (*)[4 * HH])(smem + 65648);  // 2048 B
    float (*hbuf)[HH]       = (float (*)[HH])(smem + 67696);      // 1024 B
    float (*potring)[KK]    = (float (*)[KK])(smem + 68720);      // 8192 B
    float (*xpstage)[CH * G3] = (float (*)[CH * G3])(smem + 76912); // 49152 B
    int (*maskst)[CH]       = (int (*)[CH])(smem + 126064);       // 256 B

    if (w < 3) {
        // ================= GRU producer waves =================
        const int j = l;
        float wg[HH];
#pragma unroll
        for (int i2 = 0; i2 < HH; ++i2) wg[i2] = Wr[i2 * G3 + w * HH + j];
#pragma unroll
        for (int i2 = 0; i2 < HH; ++i2) asm volatile("" : "+v"(wg[i2]));
        const float bw = gbias[G3 + w * HH + j];
        __builtin_amdgcn_s_setprio(1);
        float h = 0.f;
        __syncthreads();                                  // pre-loop barrier
        float xv0 = xpstage[0][tid];                      // xv(0)
        int m0 = maskst[0][0];                            // m(0), broadcast
        for (int i = 0; i < TT + 2; ++i) {
            if (i < TT) {
                float a0 = bw, a1 = 0.f, a2 = 0.f, a3 = 0.f;
#pragma unroll
                for (int c = 0; c < HH; c += 4) {
                    a0 += BCAST(h, c + 0) * wg[c + 0];
                    a1 += BCAST(h, c + 1) * wg[c + 1];
                    a2 += BCAST(h, c + 2) * wg[c + 2];
                    a3 += BCAST(h, c + 3) * wg[c + 3];
                }
                float a = (a0 + a1) + (a2 + a3);
                float g = (w == 2) ? a : 1.f / (1.f + __expf(-(xv0 + a)));
                gbuf[i & 1][w * HH + j] = g;
                if (w == 2) gbuf[i & 1][3 * HH + j] = xv0;
            }
            __syncthreads();
            if (i < TT) {
                float z  = gbuf[i & 1][j];
                float r  = gbuf[i & 1][HH + j];
                float rh = gbuf[i & 1][2 * HH + j];
                float xh = gbuf[i & 1][3 * HH + j];
                float y = xh + r * rh;
                float hh = 1.f - 2.f / (1.f + __expf(2.f * y));   // tanh
                float hn = z * h + (1.f - z) * hh;
                hn = (m0 != 0) ? hn : h;
                h = hn;
                if (w == 0) hbuf[i & 3][j] = hn;
                if (i < TT - 1) {                        // prefetch step i+1
                    const int t1 = i + 1;
                    xv0 = xpstage[(t1 >> 5) & 1][(t1 & 31) * G3 + tid];
                    m0  = maskst[(t1 >> 5) & 1][t1 & 31];
                }
            }
        }
    } else if (w == 3) {
        // ============ pot matvec + chunk staging wave ============
        const int k = l & 31;
        int sl = 0;
#pragma unroll
        for (int q = 0; q < 16; ++q) sl += mask[bTT + q * 64 + l];
#pragma unroll
        for (int d = 32; d >= 1; d >>= 1) sl += __shfl_xor(sl, d, 64);
        if (l == 0) out_slen[b] = (float)sl;
        float dk[HH];
#pragma unroll
        for (int i2 = 0; i2 < HH; ++i2) dk[i2] = Dk[i2 * KK + k];
#pragma unroll
        for (int i2 = 0; i2 < HH; ++i2) asm volatile("" : "+v"(dk[i2]));
        const float dbk = db[k], lbk = lb[k], rbk = rb[k];
        const float* xpg = xp + (size_t)bTT * G3;
        float* potg = out_pot + (size_t)bTT * KK;
        // wait for chunk 0 then stage it
        if (l == 0) {
            while (atomicAdd(&g_flags[b * 32], 0) == 0) __builtin_amdgcn_s_sleep(8);
        }
        __threadfence();                                  // acquire
#pragma unroll
        for (int q = 0; q < 24; ++q) {
            float4 v = *(const float4*)&xpg[q * 256 + l * 4];
            *(float4*)&xpstage[0][q * 256 + l * 4] = v;
        }
        if (l < CH) maskst[0][l] = mask[bTT + l];
        __syncthreads();                                  // pre-loop barrier
        for (int i = 0; i < TT + 2; ++i) {
            if ((i & 31) == 0) {
                const int cn = (i >> 5) + 1;              // stage chunk cn
                if (cn < 32) {
                    if (l == 0) {
                        while (atomicAdd(&g_flags[b * 32 + cn], 0) == 0)
                            __builtin_amdgcn_s_sleep(8);
                    }
                    __threadfence();                      // acquire
                    const float* src = xpg + (size_t)cn * CH * G3;
                    float* dst = &xpstage[cn & 1][0];
#pragma unroll
                    for (int q = 0; q < 24; ++q) {
                        float4 v = *(const float4*)&src[q * 256 + l * 4];
                        *(float4*)&dst[q * 256 + l * 4] = v;
                    }
                    if (l < CH) maskst[cn & 1][l] = mask[bTT + cn * CH + l];
                }
                const int cf = (i >> 5) - 2;              // flush pot chunk cf
                if (cf >= 0) {
                    const float* srcl = &potring[(cf & 1) * 32][0];
                    float* dstg = potg + (size_t)cf * CH * KK;
#pragma unroll
                    for (int q = 0; q < 4; ++q) {
                        float4 v = *(const float4*)&srcl[q * 256 + l * 4];
                        *(float4*)&dstg[q * 256 + l * 4] = v;
                    }
                }
            }
            const int t = i - 2;
            if (t >= 0 && t < TT) {
                const float4* hv4 = (const float4*)&hbuf[t & 3][0];
                float p0 = dbk, p1 = 0.f, p2 = 0.f, p3 = 0.f;
#pragma unroll
                for (int c = 0; c < 16; ++c) {
                    float4 hv = hv4[c];
                    p0 += hv.x * dk[4 * c + 0];
                    p1 += hv.y * dk[4 * c + 1];
                    p2 += hv.z * dk[4 * c + 2];
                    p3 += hv.w * dk[4 * c + 3];
                }
                float pot = (p0 + p1) + (p2 + p3);
                if (t == 0) pot += lbk;
                if (t == sl - 1) pot += rbk;
                if (l < 32) potring[t & 63][k] = pot;
            }
            __syncthreads();
        }
        // flush last pot chunk (31)
        {
            const float* srcl = &potring[(31 & 1) * 32][0];
            float* dstg = potg + (size_t)31 * CH * KK;
#pragma unroll
            for (int q = 0; q < 4; ++q) {
                float4 v = *(const float4*)&srcl[q * 256 + l * 4];
                *(float4*)&dstg[q * 256 + l * 4] = v;
            }
        }
    } else {
        // ================= viterbi wave =================
        const int k = l & 31;
        const int hf = l >> 5;
        float ccol[16];
        int addr[16];
#pragma unroll
        for (int m = 0; m < 16; ++m) {
            ccol[m] = chain[(hf * 16 + m) * KK + k];
            addr[m] = (hf * 16 + m) * 4;
        }
#pragma unroll
        for (int m = 0; m < 16; ++m) asm volatile("" : "+v"(ccol[m]));
        const int addrx = (l ^ 32) * 4;
        float s = 0.f;
        __syncthreads();                                  // pre-loop barrier
        for (int i = 0; i < TT + 2; ++i) {
            __syncthreads();
            const int t = i - 2;
            if (t >= 0 && t < TT) {
                float pot = potring[t & 63][k];
                if (t == 0) {
                    s = pot;
                } else {
                    const int si = __float_as_int(s);
                    float c[16];
#pragma unroll
                    for (int m = 0; m < 16; ++m)
                        c[m] = __int_as_float(__builtin_amdgcn_ds_bpermute(addr[m], si)) + ccol[m];
                    float v1[8]; int i1[8];
#pragma unroll
                    for (int p = 0; p < 8; ++p) {
                        bool tk = c[2 * p + 1] > c[2 * p];
                        v1[p] = tk ? c[2 * p + 1] : c[2 * p];
                        i1[p] = hf * 16 + (tk ? 2 * p + 1 : 2 * p);
                    }
                    float v2[4]; int i2[4];
#pragma unroll
                    for (int p = 0; p < 4; ++p) {
                        bool tk = v1[2 * p + 1] > v1[2 * p];
                        v2[p] = tk ? v1[2 * p + 1] : v1[2 * p];
                        i2[p] = tk ? i1[2 * p + 1] : i1[2 * p];
                    }
                    float v3[2]; int i3[2];
#pragma unroll
                    for (int p = 0; p < 2; ++p) {
                        bool tk = v2[2 * p + 1] > v2[2 * p];
                        v3[p] = tk ? v2[2 * p + 1] : v2[2 * p];
                        i3[p] = tk ? i2[2 * p + 1] : i2[2 * p];
                    }
                    bool tk = v3[1] > v3[0];
                    float bv = tk ? v3[1] : v3[0];
                    int bi = tk ? i3[1] : i3[0];
                    float ov = __int_as_float(__builtin_amdgcn_ds_bpermute(addrx, __float_as_int(bv)));
                    int   oi = __builtin_amdgcn_ds_bpermute(addrx, bi);
                    bool take = (ov > bv) || (ov == bv && oi < bi);
                    if (take) { bv = ov; bi = oi; }
                    if (l < 32) bp[(t - 1) * KK + k] = (unsigned char)bi;
                    s = bv + pot;
                }
            }
        }
        float bv = s; int bi = k;
#pragma unroll
        for (int d = 16; d >= 1; d >>= 1) {
            float ov = __shfl_xor(bv, d, 64);
            int   oi = __shfl_xor(bi, d, 64);
            bool take = (ov > bv) || (ov == bv && oi < bi);
            if (take) { bv = ov; bi = oi; }
        }
        if (l == 0) *last_tag_s = bi;
    }
    __syncthreads();
    // ---- Phase A: chunk-parallel backtrack (10 groups over 32 chunks) ----
    {
        const int k = tid & 31;
        const int grp = tid >> 5;                         // 0..9
        for (int c = grp; c < 32; c += 10) {
            int tag = k;
            for (int ll = 31; ll >= 0; --ll) {
                const int t = c * 32 + ll;
                if (t < TT - 1) tag = bp[t * KK + tag];
                table[(c * 32 + ll) * KK + k] = (unsigned char)tag;
            }
        }
    }
    __syncthreads();
    if (tid == 0) {                                       // Phase B: stitch
        int e = *last_tag_s;
        ent[31] = e;
        for (int c = 30; c >= 0; --c) { e = table[(c + 1) * 32 * KK + e]; ent[c] = e; }
    }
    __syncthreads();
    for (int t = tid; t < TT; t += 320) {                 // Phase C: emit
        const int c = t >> 5, ll = t & 31;
        out_dec[(size_t)bTT + t] = (float)table[(c * 32 + ll) * KK + ent[c]];
    }
    if (blockIdx.x == BB) {
        for (int i2 = tid; i2 < KK * KK; i2 += 320) out_chn[i2] = chain[i2];
    }
    // re-zero this batch's flags for the next launch/replay (device-scope)
    for (int i2 = tid; i2 < 32; i2 += 320) atomicExch(&g_flags[b * 32 + i2], 0);
}

// ---------------------------------------------------------------------------
extern "C" void kernel_launch(void* const* d_in, const int* in_sizes, int n_in,
                              void* d_out, int out_size, void* d_ws, size_t ws_size,
                              hipStream_t stream) {
    const float* X     = (const float*)d_in[0];
    const int*   mask  = (const int*)d_in[1];
    const float* Wk    = (const float*)d_in[2];   // [128,192]
    const float* Wr    = (const float*)d_in[3];   // [64,192]
    const float* gb    = (const float*)d_in[4];   // [2,192]
    const float* Dk    = (const float*)d_in[5];   // [64,32]
    const float* db    = (const float*)d_in[6];   // [32]
    const float* chain = (const float*)d_in[7];   // [32,32]
    const float* lb    = (const float*)d_in[8];
    const float* rb    = (const float*)d_in[9];

    float* out = (float*)d_out;
    float* out_dec  = out;                                   // [B,T]
    float* out_pot  = out + (size_t)BB * TT;                 // [B,T,K]
    float* out_slen = out + (size_t)BB * TT + (size_t)BB * TT * KK;        // [B]
    float* out_chn  = out_slen + BB;                         // [K,K]

    float* xp = (float*)d_ws;                                // [B*T,192]

    mega_kernel<<<dim3(2 * BB), dim3(320), 0, stream>>>(X, Wk, Wr, gb, mask, Dk, db,
                                                        chain, lb, rb, xp, out_pot,
                                                        out_dec, out_slen, out_chn);
}